// Round 6
// baseline (1164.426 us; speedup 1.0000x reference)
//
#include <hip/hip_runtime.h>
#include <math.h>

#define PP 196608
#define NK 8

#define O_SIGALL 589824
#define O_RGB    786432
#define O_SIG    5505024

typedef __attribute__((ext_vector_type(8))) short short8;
typedef __attribute__((ext_vector_type(4))) float f32x4;

// ---- workspace byte offsets ----
#define OW_B0 0
#define OW_B1 8192
#define OW_B2 16384
#define OW_A0 24576
#define OW_A1 40960
#define OW_A2 49152
#define OW_L  57344
#define OW_V  65536
#define OW_C0 71680
#define OW_C1 72704
#define OB_B0 73728
#define OB_A0 75776
#define OB_B1 77824
#define OB_B2 78080
#define OB_A1 78336
#define OB_A2 78592
#define OB_L  78848
#define OB_V  79104
#define OB_C0 79232
#define OB_C1 79296

// float -> bf16 bits, round-nearest-even (no __bf16 type dependence)
__device__ __forceinline__ short bfr(float f) {
    unsigned u = __builtin_bit_cast(unsigned, f);
    unsigned r = (u + 0x7FFFu + ((u >> 16) & 1u)) >> 16;
    return (short)r;
}

// stored col p (0..31 within 32-block) -> logical col offset
__device__ __forceinline__ int tau(int p) {
    return 16 * ((p >> 2) & 1) + 4 * (p >> 3) + (p & 3);
}

// positional-embedding element j (runtime index), zero for j >= jmax.
// layout: [x,y,z, sin(2^0 x..z), cos(2^0 x..z), sin(2^1 ...), ...]
// branchless: evaluates sin+cos and selects (no arrays -> no scratch).
__device__ __forceinline__ float pe_elem(int j, float c0, float c1, float c2, int jmax) {
    int r = j - 3;
    int rf = r < 0 ? 0 : r;
    int f = rf / 6;          // 0..4 (magic-mul)
    int t = rf - 6 * f;      // 0..5
    int comp = (j < 3) ? j : (t >= 3 ? t - 3 : t);
    float c = (comp == 0) ? c0 : ((comp == 1) ? c1 : c2);
    float x = c * (float)(1 << f);
    float val = (t < 3) ? sinf(x) : cosf(x);
    if (j < 3) val = c;
    return (j < jmax) ? val : 0.f;
}

#define MFMA(a, b, c) __builtin_amdgcn_mfma_f32_16x16x32_bf16(a, b, c, 0, 0, 0)

// ================= prep kernel =================
__global__ void prep_kernel(
    const float* __restrict__ slots,
    const float* __restrict__ Wb0, const float* __restrict__ bb0,
    const float* __restrict__ Wb1, const float* __restrict__ bb1,
    const float* __restrict__ Wb2, const float* __restrict__ bb2,
    const float* __restrict__ Wa0, const float* __restrict__ ba0,
    const float* __restrict__ Wa1, const float* __restrict__ ba1,
    const float* __restrict__ Wa2, const float* __restrict__ ba2,
    const float* __restrict__ Wl,  const float* __restrict__ bl,
    const float* __restrict__ Wv,  const float* __restrict__ bv,
    const float* __restrict__ Wc0, const float* __restrict__ bc0,
    const float* __restrict__ Wc1, const float* __restrict__ bc1,
    char* __restrict__ ws)
{
    short* wsS = (short*)ws;
    float* wsF = (float*)ws;
    const int tid = threadIdx.x;

    // b0: [64][64], real cols 33 (emb part of Wb0)
    for (int idx = tid; idx < 64 * 64; idx += 256) {
        int j = idx >> 6, C = idx & 63;
        int lc = (C & ~31) + tau(C & 31);
        wsS[OW_B0 / 2 + idx] = bfr(lc < 33 ? Wb0[j * 97 + lc] : 0.f);
    }
    // b1,b2,a1,a2,lat: [64][64] full
    for (int idx = tid; idx < 64 * 64; idx += 256) {
        int j = idx >> 6, C = idx & 63;
        int lc = (C & ~31) + tau(C & 31);
        float vb1 = Wb1[j * 64 + lc], vb2 = Wb2[j * 64 + lc];
        float va1 = Wa1[j * 64 + lc], va2 = Wa2[j * 64 + lc];
        float vl  = Wl [j * 64 + lc];
        wsS[OW_B1 / 2 + idx] = bfr(vb1);
        wsS[OW_B2 / 2 + idx] = bfr(vb2);
        wsS[OW_A1 / 2 + idx] = bfr(va1);
        wsS[OW_A2 / 2 + idx] = bfr(va2);
        wsS[OW_L  / 2 + idx] = bfr(vl);
    }
    // a0: [64][128]; cols 0..32 = emb part, 64..127 = skip part (src cols 97..160)
    for (int idx = tid; idx < 64 * 128; idx += 256) {
        int j = idx >> 7, C = idx & 127;
        int lc = (C & ~31) + tau(C & 31);
        float v = 0.f;
        if (lc < 33) v = Wa0[j * 161 + lc];
        else if (lc >= 64) v = Wa0[j * 161 + 33 + lc];  // 97 + (lc-64)
        wsS[OW_A0 / 2 + idx] = bfr(v);
    }
    // views: [32][96]; cols 0..63 latent, 64..84 view-emb
    for (int idx = tid; idx < 32 * 96; idx += 256) {
        int j = idx / 96, C = idx % 96;
        int lc = (C & ~31) + tau(C & 31);
        wsS[OW_V / 2 + idx] = bfr(lc < 85 ? Wv[j * 85 + lc] : 0.f);
    }
    // c0: [16][32]
    for (int idx = tid; idx < 16 * 32; idx += 256) {
        int j = idx >> 5, C = idx & 31;
        int lc = tau(C);
        wsS[OW_C0 / 2 + idx] = bfr(Wc0[j * 32 + lc]);
    }
    // c1: [16][32]; 3 real rows, 16 real cols
    for (int idx = tid; idx < 16 * 32; idx += 256) {
        int j = idx >> 5, C = idx & 31;
        int lc = tau(C);
        wsS[OW_C1 / 2 + idx] = bfr((j < 3 && lc < 16) ? Wc1[j * 16 + lc] : 0.f);
    }
    // slot-folded biases: b0 / a0 (slot features at src cols 33..96)
    for (int idx = tid; idx < 512; idx += 256) {
        int k = idx >> 6, j = idx & 63;
        const float* sl = slots + k * 64;
        float a = bb0[j];
        const float* w0 = Wb0 + j * 97 + 33;
        for (int i = 0; i < 64; ++i) a = fmaf(w0[i], sl[i], a);
        wsF[OB_B0 / 4 + idx] = a;
        float b = ba0[j];
        const float* w1 = Wa0 + j * 161 + 33;
        for (int i = 0; i < 64; ++i) b = fmaf(w1[i], sl[i], b);
        wsF[OB_A0 / 4 + idx] = b;
    }
    // plain biases
    for (int idx = tid; idx < 64; idx += 256) {
        wsF[OB_B1 / 4 + idx] = bb1[idx];
        wsF[OB_B2 / 4 + idx] = bb2[idx];
        wsF[OB_A1 / 4 + idx] = ba1[idx];
        wsF[OB_A2 / 4 + idx] = ba2[idx];
        wsF[OB_L  / 4 + idx] = bl[idx];
        if (idx < 32) wsF[OB_V / 4 + idx] = bv[idx];
        if (idx < 16) wsF[OB_C0 / 4 + idx] = bc0[idx];
        if (idx < 16) wsF[OB_C1 / 4 + idx] = (idx < 3) ? bc1[idx] : 0.f;
    }
}

// ================= main kernel helpers =================
template<int NT, int NS, int KP>
__device__ __forceinline__ void loadA(const short* W, int l15, int g8, short8 (&A)[NT][NS]) {
    #pragma unroll
    for (int t = 0; t < NT; ++t)
        #pragma unroll
        for (int s = 0; s < NS; ++s)
            A[t][s] = *(const short8*)(W + (16 * t + l15) * KP + 32 * s + g8);
}

template<bool RELU>
__device__ __forceinline__ void pack4(const f32x4 (&c)[4], short8 (&o)[2]) {
    #pragma unroll
    for (int s = 0; s < 2; ++s) {
        short8 f;
        #pragma unroll
        for (int i = 0; i < 8; ++i) {
            float v = c[2 * s + (i >> 2)][i & 3];
            if (RELU) v = fmaxf(v, 0.f);
            f[i] = bfr(v);
        }
        o[s] = f;
    }
}

__device__ __forceinline__ void layer64(const short8 (&A)[4][2], const short8 (&B)[2],
                                        const float* bias, int g4, f32x4 (&c)[4]) {
    #pragma unroll
    for (int t = 0; t < 4; ++t) c[t] = *(const f32x4*)(bias + 16 * t + g4);
    #pragma unroll
    for (int s = 0; s < 2; ++s)
        #pragma unroll
        for (int t = 0; t < 4; ++t)
            c[t] = MFMA(A[t][s], B[s], c[t]);
}

// ================= main kernel =================
__global__ __launch_bounds__(256, 4) void decoder_kernel(
    const float* __restrict__ coor,
    const float* __restrict__ view,
    const float* __restrict__ dens,
    const float* __restrict__ act_shift,
    const int*   __restrict__ ray_id,
    const char*  __restrict__ ws,
    float* __restrict__ out)
{
    const short* wsS = (const short*)ws;
    const float* wsF = (const float*)ws;
    const int tid = threadIdx.x;
    const int l   = tid & 63;
    const int l15 = l & 15;
    const int g   = (l >> 4) & 3;
    const int g8  = g * 8;
    const int g4  = g * 4;
    const int p   = blockIdx.x * 64 + (tid >> 6) * 16 + l15;

    // ---- positional embedding fragments, computed element-direct (no arrays) ----
    // lane needs j = 16*(i>>2) + 4g + (i&3) for embB0 (all j<32),
    // plus j=32 (cos(16*z)) on g==0 lanes as elem 0 of embB1.
    float c0 = coor[p * 3 + 0], c1 = coor[p * 3 + 1], c2 = coor[p * 3 + 2];
    short8 embB0, embB1;
    #pragma unroll
    for (int i = 0; i < 8; ++i) {
        int j = ((i >> 2) * 16) + 4 * g + (i & 3);
        embB0[i] = bfr(pe_elem(j, c0, c1, c2, 33));
    }
    {
        float v32 = cosf(c2 * 16.f);
        #pragma unroll
        for (int i = 0; i < 8; ++i) embB1[i] = 0;
        embB1[0] = (g == 0) ? bfr(v32) : (short)0;
    }
    // ---- view embedding fragment (jmax=21) ----
    short8 vembB;
    {
        int rid = ray_id[p];
        float v0 = view[rid * 3 + 0], v1 = view[rid * 3 + 1], v2 = view[rid * 3 + 2];
        #pragma unroll
        for (int i = 0; i < 8; ++i) {
            int j = ((i >> 2) * 16) + 4 * g + (i & 3);
            vembB[i] = bfr(pe_elem(j, v0, v1, v2, 21));
        }
    }

    // ---- masks / sigma ----
    float w[8], mk[8];
    float msum = 0.f;
    float shift = act_shift[0];
    #pragma unroll
    for (int k = 0; k < 8; ++k) {
        float d = dens[k * PP + p] + shift;
        float sp = fmaxf(d, 0.f) + log1pf(expf(-fabsf(d)));
        mk[k] = sp; msum += sp;
        if (l < 16) out[O_SIG + k * PP + p] = sp;
    }
    float inv = 1.f / (msum + 1e-5f);
    float mk2 = 0.f;
    #pragma unroll
    for (int k = 0; k < 8; ++k) { w[k] = mk[k] * inv; mk2 += mk[k] * mk[k]; }
    if (l < 16) out[O_SIGALL + p] = mk2 * inv;

    // ---- MLP over 8 slots, 4 at a time ----
    float rgbA0 = 0.f, rgbA1 = 0.f, rgbA2 = 0.f;
    short8 act[4][2];

    #pragma unroll 1
    for (int kq = 0; kq < 2; ++kq) {
        const float* BB0 = wsF + OB_B0 / 4 + kq * 256;
        const float* BA0 = wsF + OB_A0 / 4 + kq * 256;

        { // b0: emb -> 64
            short8 A[4][2]; loadA<4, 2, 64>(wsS + OW_B0 / 2, l15, g8, A);
            #pragma unroll
            for (int si = 0; si < 4; ++si) {
                f32x4 c[4];
                #pragma unroll
                for (int t = 0; t < 4; ++t) c[t] = *(const f32x4*)(BB0 + si * 64 + 16 * t + g4);
                #pragma unroll
                for (int t = 0; t < 4; ++t) {
                    c[t] = MFMA(A[t][0], embB0, c[t]);
                    c[t] = MFMA(A[t][1], embB1, c[t]);
                }
                pack4<true>(c, act[si]);
            }
        }
        { // b1
            short8 A[4][2]; loadA<4, 2, 64>(wsS + OW_B1 / 2, l15, g8, A);
            #pragma unroll
            for (int si = 0; si < 4; ++si) {
                f32x4 c[4];
                layer64(A, act[si], wsF + OB_B1 / 4, g4, c);
                pack4<true>(c, act[si]);
            }
        }
        { // b2
            short8 A[4][2]; loadA<4, 2, 64>(wsS + OW_B2 / 2, l15, g8, A);
            #pragma unroll
            for (int si = 0; si < 4; ++si) {
                f32x4 c[4];
                layer64(A, act[si], wsF + OB_B2 / 4, g4, c);
                pack4<true>(c, act[si]);
            }
        }
        { // a0: [emb | skip] -> 64
            short8 A[4][4]; loadA<4, 4, 128>(wsS + OW_A0 / 2, l15, g8, A);
            #pragma unroll
            for (int si = 0; si < 4; ++si) {
                f32x4 c[4];
                #pragma unroll
                for (int t = 0; t < 4; ++t) c[t] = *(const f32x4*)(BA0 + si * 64 + 16 * t + g4);
                #pragma unroll
                for (int t = 0; t < 4; ++t) {
                    c[t] = MFMA(A[t][0], embB0, c[t]);
                    c[t] = MFMA(A[t][1], embB1, c[t]);
                    c[t] = MFMA(A[t][2], act[si][0], c[t]);
                    c[t] = MFMA(A[t][3], act[si][1], c[t]);
                }
                pack4<true>(c, act[si]);
            }
        }
        { // a1
            short8 A[4][2]; loadA<4, 2, 64>(wsS + OW_A1 / 2, l15, g8, A);
            #pragma unroll
            for (int si = 0; si < 4; ++si) {
                f32x4 c[4];
                layer64(A, act[si], wsF + OB_A1 / 4, g4, c);
                pack4<true>(c, act[si]);
            }
        }
        { // a2
            short8 A[4][2]; loadA<4, 2, 64>(wsS + OW_A2 / 2, l15, g8, A);
            #pragma unroll
            for (int si = 0; si < 4; ++si) {
                f32x4 c[4];
                layer64(A, act[si], wsF + OB_A2 / 4, g4, c);
                pack4<true>(c, act[si]);
            }
        }
        { // latent (no relu)
            short8 A[4][2]; loadA<4, 2, 64>(wsS + OW_L / 2, l15, g8, A);
            #pragma unroll
            for (int si = 0; si < 4; ++si) {
                f32x4 c[4];
                layer64(A, act[si], wsF + OB_L / 4, g4, c);
                pack4<false>(c, act[si]);
            }
        }
        { // tail: views -> c0 -> c1 -> rgb
            short8 AV[2][3];  loadA<2, 3, 96>(wsS + OW_V  / 2, l15, g8, AV);
            short8 AC0[1][1]; loadA<1, 1, 32>(wsS + OW_C0 / 2, l15, g8, AC0);
            short8 AC1[1][1]; loadA<1, 1, 32>(wsS + OW_C1 / 2, l15, g8, AC1);
            #pragma unroll
            for (int si = 0; si < 4; ++si) {
                int slot = 4 * kq + si;
                f32x4 cv[2];
                #pragma unroll
                for (int t = 0; t < 2; ++t) cv[t] = *(const f32x4*)(wsF + OB_V / 4 + 16 * t + g4);
                #pragma unroll
                for (int t = 0; t < 2; ++t) {
                    cv[t] = MFMA(AV[t][0], act[si][0], cv[t]);
                    cv[t] = MFMA(AV[t][1], act[si][1], cv[t]);
                    cv[t] = MFMA(AV[t][2], vembB, cv[t]);
                }
                short8 vB;
                #pragma unroll
                for (int i = 0; i < 8; ++i) vB[i] = bfr(fmaxf(cv[i >> 2][i & 3], 0.f));
                f32x4 cc = *(const f32x4*)(wsF + OB_C0 / 4 + g4);
                cc = MFMA(AC0[0][0], vB, cc);
                short8 cB;
                #pragma unroll
                for (int i = 0; i < 8; ++i) cB[i] = (i < 4) ? bfr(fmaxf(cc[i], 0.f)) : (short)0;
                f32x4 cf = *(const f32x4*)(wsF + OB_C1 / 4 + g4);
                cf = MFMA(AC1[0][0], cB, cf);
                float r0 = (tanhf(cf[0]) + 1.f) * 0.5f;
                float r1 = (tanhf(cf[1]) + 1.f) * 0.5f;
                float r2 = (tanhf(cf[2]) + 1.f) * 0.5f;
                float wlo = w[si], whi = w[si + 4];
                float wsel = kq ? whi : wlo;
                rgbA0 = fmaf(wsel, r0, rgbA0);
                rgbA1 = fmaf(wsel, r1, rgbA1);
                rgbA2 = fmaf(wsel, r2, rgbA2);
                if (l < 16) {
                    int base = O_RGB + (slot * PP + p) * 3;
                    out[base + 0] = r0; out[base + 1] = r1; out[base + 2] = r2;
                }
            }
        }
    }
    if (l < 16) {
        out[p * 3 + 0] = rgbA0;
        out[p * 3 + 1] = rgbA1;
        out[p * 3 + 2] = rgbA2;
    }
}

extern "C" void kernel_launch(void* const* d_in, const int* in_sizes, int n_in,
                              void* d_out, int out_size, void* d_ws, size_t ws_size,
                              hipStream_t stream) {
    const float* coor  = (const float*)d_in[0];
    const float* view  = (const float*)d_in[1];
    const float* slots = (const float*)d_in[2];
    const float* dens  = (const float*)d_in[3];
    const float* shf   = (const float*)d_in[4];
    const float* Wb0 = (const float*)d_in[5];  const float* bb0 = (const float*)d_in[6];
    const float* Wb1 = (const float*)d_in[7];  const float* bb1 = (const float*)d_in[8];
    const float* Wb2 = (const float*)d_in[9];  const float* bb2 = (const float*)d_in[10];
    const float* Wa0 = (const float*)d_in[11]; const float* ba0 = (const float*)d_in[12];
    const float* Wa1 = (const float*)d_in[13]; const float* ba1 = (const float*)d_in[14];
    const float* Wa2 = (const float*)d_in[15]; const float* ba2 = (const float*)d_in[16];
    const float* Wl  = (const float*)d_in[17]; const float* bl  = (const float*)d_in[18];
    const float* Wv  = (const float*)d_in[19]; const float* bv  = (const float*)d_in[20];
    const float* Wc0 = (const float*)d_in[21]; const float* bc0 = (const float*)d_in[22];
    const float* Wc1 = (const float*)d_in[23]; const float* bc1 = (const float*)d_in[24];
    const int*   ray = (const int*)d_in[25];
    float* out = (float*)d_out;

    prep_kernel<<<dim3(1), dim3(256), 0, stream>>>(
        slots, Wb0, bb0, Wb1, bb1, Wb2, bb2,
        Wa0, ba0, Wa1, ba1, Wa2, ba2,
        Wl, bl, Wv, bv, Wc0, bc0, Wc1, bc1, (char*)d_ws);

    decoder_kernel<<<dim3(PP / 64), dim3(256), 0, stream>>>(
        coor, view, dens, shf, ray, (const char*)d_ws, out);
}

// Round 8
// 644.354 us; speedup vs baseline: 1.8071x; 1.8071x over previous
//
#include <hip/hip_runtime.h>
#include <math.h>

#define PP 196608
#define NK 8

#define O_SIGALL 589824
#define O_RGB    786432
#define O_SIG    5505024

typedef __attribute__((ext_vector_type(8))) short short8;
typedef __attribute__((ext_vector_type(4))) float f32x4;

// ---- workspace byte offsets ----
#define OW_B0 0
#define OW_B1 8192
#define OW_B2 16384
#define OW_A0 24576
#define OW_A1 40960
#define OW_A2 49152
#define OW_L  57344
#define OW_V  65536
#define OW_C0 71680
#define OW_C1 72704
#define OB_B0 73728
#define OB_A0 75776
#define OB_B1 77824
#define OB_B2 78080
#define OB_A1 78336
#define OB_A2 78592
#define OB_L  78848
#define OB_V  79104
#define OB_C0 79232
#define OB_C1 79296
#define OB_W32B0 79360
#define OB_W32A0 79616

// float -> bf16 bits, round-nearest-even
__device__ __forceinline__ short bfr(float f) {
    unsigned u = __builtin_bit_cast(unsigned, f);
    unsigned r = (u + 0x7FFFu + ((u >> 16) & 1u)) >> 16;
    return (short)r;
}

// stored col p (0..31 within 32-block) -> logical col offset
__device__ __forceinline__ int tau(int p) {
    return 16 * ((p >> 2) & 1) + 4 * (p >> 3) + (p & 3);
}

// positional-embedding element j (runtime index), zero for j >= jmax.
__device__ __forceinline__ float pe_elem(int j, float c0, float c1, float c2, int jmax) {
    int r = j - 3;
    int rf = r < 0 ? 0 : r;
    int f = rf / 6;
    int t = rf - 6 * f;
    int comp = (j < 3) ? j : (t >= 3 ? t - 3 : t);
    float c = (comp == 0) ? c0 : ((comp == 1) ? c1 : c2);
    float x = c * (float)(1 << f);
    float val = (t < 3) ? sinf(x) : cosf(x);
    if (j < 3) val = c;
    return (j < jmax) ? val : 0.f;
}

#define MFMA(a, b, c) __builtin_amdgcn_mfma_f32_16x16x32_bf16(a, b, c, 0, 0, 0)

// ================= prep kernel =================
__global__ void prep_kernel(
    const float* __restrict__ slots,
    const float* __restrict__ Wb0, const float* __restrict__ bb0,
    const float* __restrict__ Wb1, const float* __restrict__ bb1,
    const float* __restrict__ Wb2, const float* __restrict__ bb2,
    const float* __restrict__ Wa0, const float* __restrict__ ba0,
    const float* __restrict__ Wa1, const float* __restrict__ ba1,
    const float* __restrict__ Wa2, const float* __restrict__ ba2,
    const float* __restrict__ Wl,  const float* __restrict__ bl,
    const float* __restrict__ Wv,  const float* __restrict__ bv,
    const float* __restrict__ Wc0, const float* __restrict__ bc0,
    const float* __restrict__ Wc1, const float* __restrict__ bc1,
    char* __restrict__ ws)
{
    short* wsS = (short*)ws;
    float* wsF = (float*)ws;
    const int tid = threadIdx.x;

    // b0: [64][64], emb cols; only stored cols 0..31 used by main (col 32 via VALU)
    for (int idx = tid; idx < 64 * 64; idx += 256) {
        int j = idx >> 6, C = idx & 63;
        int lc = (C & ~31) + tau(C & 31);
        wsS[OW_B0 / 2 + idx] = bfr(lc < 33 ? Wb0[j * 97 + lc] : 0.f);
    }
    // b1,b2,a1,a2,lat: [64][64] full
    for (int idx = tid; idx < 64 * 64; idx += 256) {
        int j = idx >> 6, C = idx & 63;
        int lc = (C & ~31) + tau(C & 31);
        wsS[OW_B1 / 2 + idx] = bfr(Wb1[j * 64 + lc]);
        wsS[OW_B2 / 2 + idx] = bfr(Wb2[j * 64 + lc]);
        wsS[OW_A1 / 2 + idx] = bfr(Wa1[j * 64 + lc]);
        wsS[OW_A2 / 2 + idx] = bfr(Wa2[j * 64 + lc]);
        wsS[OW_L  / 2 + idx] = bfr(Wl [j * 64 + lc]);
    }
    // a0: [64][128]; cols 0..31 emb-lo, 64..127 skip (src cols 97..160)
    for (int idx = tid; idx < 64 * 128; idx += 256) {
        int j = idx >> 7, C = idx & 127;
        int lc = (C & ~31) + tau(C & 31);
        float v = 0.f;
        if (lc < 33) v = Wa0[j * 161 + lc];
        else if (lc >= 64) v = Wa0[j * 161 + 33 + lc];
        wsS[OW_A0 / 2 + idx] = bfr(v);
    }
    // views: [32][96]
    for (int idx = tid; idx < 32 * 96; idx += 256) {
        int j = idx / 96, C = idx % 96;
        int lc = (C & ~31) + tau(C & 31);
        wsS[OW_V / 2 + idx] = bfr(lc < 85 ? Wv[j * 85 + lc] : 0.f);
    }
    // c0: [16][32]
    for (int idx = tid; idx < 16 * 32; idx += 256) {
        int j = idx >> 5, C = idx & 31;
        wsS[OW_C0 / 2 + idx] = bfr(Wc0[j * 32 + tau(C)]);
    }
    // c1: [16][32]
    for (int idx = tid; idx < 16 * 32; idx += 256) {
        int j = idx >> 5, C = idx & 31;
        int lc = tau(C);
        wsS[OW_C1 / 2 + idx] = bfr((j < 3 && lc < 16) ? Wc1[j * 16 + lc] : 0.f);
    }
    // slot-folded biases
    for (int idx = tid; idx < 512; idx += 256) {
        int k = idx >> 6, j = idx & 63;
        const float* sl = slots + k * 64;
        float a = bb0[j];
        const float* w0 = Wb0 + j * 97 + 33;
        for (int i = 0; i < 64; ++i) a = fmaf(w0[i], sl[i], a);
        wsF[OB_B0 / 4 + idx] = a;
        float b = ba0[j];
        const float* w1 = Wa0 + j * 161 + 33;
        for (int i = 0; i < 64; ++i) b = fmaf(w1[i], sl[i], b);
        wsF[OB_A0 / 4 + idx] = b;
    }
    // plain biases + col-32 weight tables (fp32)
    for (int idx = tid; idx < 64; idx += 256) {
        wsF[OB_B1 / 4 + idx] = bb1[idx];
        wsF[OB_B2 / 4 + idx] = bb2[idx];
        wsF[OB_A1 / 4 + idx] = ba1[idx];
        wsF[OB_A2 / 4 + idx] = ba2[idx];
        wsF[OB_L  / 4 + idx] = bl[idx];
        wsF[OB_W32B0 / 4 + idx] = Wb0[idx * 97 + 32];
        wsF[OB_W32A0 / 4 + idx] = Wa0[idx * 161 + 32];
        if (idx < 32) wsF[OB_V / 4 + idx] = bv[idx];
        if (idx < 16) wsF[OB_C0 / 4 + idx] = bc0[idx];
        if (idx < 16) wsF[OB_C1 / 4 + idx] = (idx < 3) ? bc1[idx] : 0.f;
    }
}

// ================= main kernel helpers =================
template<int NT, int NS, int KP>
__device__ __forceinline__ void loadA(const short* W, int l15, int g8, short8 (&A)[NT][NS]) {
    #pragma unroll
    for (int t = 0; t < NT; ++t)
        #pragma unroll
        for (int s = 0; s < NS; ++s)
            A[t][s] = *(const short8*)(W + (16 * t + l15) * KP + 32 * s + g8);
}

template<bool RELU>
__device__ __forceinline__ void pack4(const f32x4 (&c)[4], short8 (&o)[2]) {
    #pragma unroll
    for (int s = 0; s < 2; ++s) {
        short8 f;
        #pragma unroll
        for (int i = 0; i < 8; ++i) {
            float v = c[2 * s + (i >> 2)][i & 3];
            if (RELU) v = fmaxf(v, 0.f);
            f[i] = bfr(v);
        }
        o[s] = f;
    }
}

__device__ __forceinline__ void layer64(const short8 (&A)[4][2], const short8 (&B)[2],
                                        const float* bias, int g4, f32x4 (&c)[4]) {
    #pragma unroll
    for (int t = 0; t < 4; ++t) c[t] = *(const f32x4*)(bias + 16 * t + g4);
    #pragma unroll
    for (int s = 0; s < 2; ++s)
        #pragma unroll
        for (int t = 0; t < 4; ++t)
            c[t] = MFMA(A[t][s], B[s], c[t]);
}

// ================= main kernel =================
__global__ __launch_bounds__(256, 2) void decoder_kernel(
    const float* __restrict__ coor,
    const float* __restrict__ view,
    const float* __restrict__ dens,
    const float* __restrict__ act_shift,
    const int*   __restrict__ ray_id,
    const char*  __restrict__ ws,
    float* __restrict__ out)
{
    const short* wsS = (const short*)ws;
    const float* wsF = (const float*)ws;
    const int tid = threadIdx.x;
    const int l   = tid & 63;
    const int l15 = l & 15;
    const int g   = (l >> 4) & 3;
    const int g8  = g * 8;
    const int g4  = g * 4;
    const int p   = blockIdx.x * 64 + (tid >> 6) * 16 + l15;

    // ---- pos-emb fragment (cols 0..31) + col-32 scalar ----
    short8 embB0;
    float cosv;
    {
        float c0 = coor[p * 3 + 0], c1 = coor[p * 3 + 1], c2 = coor[p * 3 + 2];
        #pragma unroll
        for (int i = 0; i < 8; ++i) {
            int j = ((i >> 2) * 16) + 4 * g + (i & 3);
            embB0[i] = bfr(pe_elem(j, c0, c1, c2, 33));
        }
        cosv = cosf(c2 * 16.f);   // logical input 32
    }
    // ---- view embedding fragment (jmax=21) ----
    short8 vembB;
    {
        int rid = ray_id[p];
        float v0 = view[rid * 3 + 0], v1 = view[rid * 3 + 1], v2 = view[rid * 3 + 2];
        #pragma unroll
        for (int i = 0; i < 8; ++i) {
            int j = ((i >> 2) * 16) + 4 * g + (i & 3);
            vembB[i] = bfr(pe_elem(j, v0, v1, v2, 21));
        }
    }

    // ---- masks / sigma ----
    float w[8];
    {
        float mk[8], msum = 0.f;
        float shift = act_shift[0];
        #pragma unroll
        for (int k = 0; k < 8; ++k) {
            float d = dens[k * PP + p] + shift;
            float sp = fmaxf(d, 0.f) + log1pf(expf(-fabsf(d)));
            mk[k] = sp; msum += sp;
            if (l < 16) out[O_SIG + k * PP + p] = sp;
        }
        float inv = 1.f / (msum + 1e-5f);
        float mk2 = 0.f;
        #pragma unroll
        for (int k = 0; k < 8; ++k) { w[k] = mk[k] * inv; mk2 += mk[k] * mk[k]; }
        if (l < 16) out[O_SIGALL + p] = mk2 * inv;
    }

    // ---- MLP over 8 slots, 2 at a time (low register pressure) ----
    float rgbA0 = 0.f, rgbA1 = 0.f, rgbA2 = 0.f;
    short8 act[2][2];

    #pragma unroll 1
    for (int kq = 0; kq < 4; ++kq) {
        const float* BB0 = wsF + OB_B0 / 4 + kq * 128;
        const float* BA0 = wsF + OB_A0 / 4 + kq * 128;

        { // b0: emb(32 via MFMA) + col32(VALU) -> 64
            short8 A[4];
            #pragma unroll
            for (int t = 0; t < 4; ++t)
                A[t] = *(const short8*)(wsS + OW_B0 / 2 + (16 * t + l15) * 64 + g8);
            f32x4 wv[4];
            #pragma unroll
            for (int t = 0; t < 4; ++t) wv[t] = *(const f32x4*)(wsF + OB_W32B0 / 4 + 16 * t + g4);
            #pragma unroll
            for (int si = 0; si < 2; ++si) {
                f32x4 c[4];
                #pragma unroll
                for (int t = 0; t < 4; ++t) c[t] = *(const f32x4*)(BB0 + si * 64 + 16 * t + g4);
                #pragma unroll
                for (int t = 0; t < 4; ++t) c[t] = MFMA(A[t], embB0, c[t]);
                #pragma unroll
                for (int t = 0; t < 4; ++t)
                    #pragma unroll
                    for (int i = 0; i < 4; ++i) c[t][i] = fmaf(wv[t][i], cosv, c[t][i]);
                pack4<true>(c, act[si]);
            }
        }
        { // b1
            short8 A[4][2]; loadA<4, 2, 64>(wsS + OW_B1 / 2, l15, g8, A);
            #pragma unroll
            for (int si = 0; si < 2; ++si) {
                f32x4 c[4];
                layer64(A, act[si], wsF + OB_B1 / 4, g4, c);
                pack4<true>(c, act[si]);
            }
        }
        { // b2
            short8 A[4][2]; loadA<4, 2, 64>(wsS + OW_B2 / 2, l15, g8, A);
            #pragma unroll
            for (int si = 0; si < 2; ++si) {
                f32x4 c[4];
                layer64(A, act[si], wsF + OB_B2 / 4, g4, c);
                pack4<true>(c, act[si]);
            }
        }
        { // a0: emb-lo(MFMA) + col32(VALU) + skip(MFMA) -> 64
            short8 A[4][3];
            #pragma unroll
            for (int t = 0; t < 4; ++t) {
                A[t][0] = *(const short8*)(wsS + OW_A0 / 2 + (16 * t + l15) * 128 + 0  + g8);
                A[t][1] = *(const short8*)(wsS + OW_A0 / 2 + (16 * t + l15) * 128 + 64 + g8);
                A[t][2] = *(const short8*)(wsS + OW_A0 / 2 + (16 * t + l15) * 128 + 96 + g8);
            }
            f32x4 wv[4];
            #pragma unroll
            for (int t = 0; t < 4; ++t) wv[t] = *(const f32x4*)(wsF + OB_W32A0 / 4 + 16 * t + g4);
            #pragma unroll
            for (int si = 0; si < 2; ++si) {
                f32x4 c[4];
                #pragma unroll
                for (int t = 0; t < 4; ++t) c[t] = *(const f32x4*)(BA0 + si * 64 + 16 * t + g4);
                #pragma unroll
                for (int t = 0; t < 4; ++t) {
                    c[t] = MFMA(A[t][0], embB0, c[t]);
                    c[t] = MFMA(A[t][1], act[si][0], c[t]);
                    c[t] = MFMA(A[t][2], act[si][1], c[t]);
                }
                #pragma unroll
                for (int t = 0; t < 4; ++t)
                    #pragma unroll
                    for (int i = 0; i < 4; ++i) c[t][i] = fmaf(wv[t][i], cosv, c[t][i]);
                pack4<true>(c, act[si]);
            }
        }
        { // a1
            short8 A[4][2]; loadA<4, 2, 64>(wsS + OW_A1 / 2, l15, g8, A);
            #pragma unroll
            for (int si = 0; si < 2; ++si) {
                f32x4 c[4];
                layer64(A, act[si], wsF + OB_A1 / 4, g4, c);
                pack4<true>(c, act[si]);
            }
        }
        { // a2
            short8 A[4][2]; loadA<4, 2, 64>(wsS + OW_A2 / 2, l15, g8, A);
            #pragma unroll
            for (int si = 0; si < 2; ++si) {
                f32x4 c[4];
                layer64(A, act[si], wsF + OB_A2 / 4, g4, c);
                pack4<true>(c, act[si]);
            }
        }
        { // latent (no relu)
            short8 A[4][2]; loadA<4, 2, 64>(wsS + OW_L / 2, l15, g8, A);
            #pragma unroll
            for (int si = 0; si < 2; ++si) {
                f32x4 c[4];
                layer64(A, act[si], wsF + OB_L / 4, g4, c);
                pack4<false>(c, act[si]);
            }
        }
        { // tail: views -> c0 -> c1 -> rgb
            short8 AV[2][3];  loadA<2, 3, 96>(wsS + OW_V  / 2, l15, g8, AV);
            short8 AC0[1][1]; loadA<1, 1, 32>(wsS + OW_C0 / 2, l15, g8, AC0);
            short8 AC1[1][1]; loadA<1, 1, 32>(wsS + OW_C1 / 2, l15, g8, AC1);
            #pragma unroll
            for (int si = 0; si < 2; ++si) {
                int slot = 2 * kq + si;
                f32x4 cv[2];
                #pragma unroll
                for (int t = 0; t < 2; ++t) cv[t] = *(const f32x4*)(wsF + OB_V / 4 + 16 * t + g4);
                #pragma unroll
                for (int t = 0; t < 2; ++t) {
                    cv[t] = MFMA(AV[t][0], act[si][0], cv[t]);
                    cv[t] = MFMA(AV[t][1], act[si][1], cv[t]);
                    cv[t] = MFMA(AV[t][2], vembB, cv[t]);
                }
                short8 vB;
                #pragma unroll
                for (int i = 0; i < 8; ++i) vB[i] = bfr(fmaxf(cv[i >> 2][i & 3], 0.f));
                f32x4 cc = *(const f32x4*)(wsF + OB_C0 / 4 + g4);
                cc = MFMA(AC0[0][0], vB, cc);
                short8 cB;
                #pragma unroll
                for (int i = 0; i < 8; ++i) cB[i] = (i < 4) ? bfr(fmaxf(cc[i], 0.f)) : (short)0;
                f32x4 cf = *(const f32x4*)(wsF + OB_C1 / 4 + g4);
                cf = MFMA(AC1[0][0], cB, cf);
                float r0 = (tanhf(cf[0]) + 1.f) * 0.5f;
                float r1 = (tanhf(cf[1]) + 1.f) * 0.5f;
                float r2 = (tanhf(cf[2]) + 1.f) * 0.5f;
                // static select of w[2*kq+si] (no runtime array index)
                float t0 = (kq & 1) ? w[2 + si] : w[si];
                float t1 = (kq & 1) ? w[6 + si] : w[4 + si];
                float wsel = (kq & 2) ? t1 : t0;
                rgbA0 = fmaf(wsel, r0, rgbA0);
                rgbA1 = fmaf(wsel, r1, rgbA1);
                rgbA2 = fmaf(wsel, r2, rgbA2);
                if (l < 16) {
                    int base = O_RGB + (slot * PP + p) * 3;
                    out[base + 0] = r0; out[base + 1] = r1; out[base + 2] = r2;
                }
            }
        }
    }
    if (l < 16) {
        out[p * 3 + 0] = rgbA0;
        out[p * 3 + 1] = rgbA1;
        out[p * 3 + 2] = rgbA2;
    }
}

extern "C" void kernel_launch(void* const* d_in, const int* in_sizes, int n_in,
                              void* d_out, int out_size, void* d_ws, size_t ws_size,
                              hipStream_t stream) {
    const float* coor  = (const float*)d_in[0];
    const float* view  = (const float*)d_in[1];
    const float* slots = (const float*)d_in[2];
    const float* dens  = (const float*)d_in[3];
    const float* shf   = (const float*)d_in[4];
    const float* Wb0 = (const float*)d_in[5];  const float* bb0 = (const float*)d_in[6];
    const float* Wb1 = (const float*)d_in[7];  const float* bb1 = (const float*)d_in[8];
    const float* Wb2 = (const float*)d_in[9];  const float* bb2 = (const float*)d_in[10];
    const float* Wa0 = (const float*)d_in[11]; const float* ba0 = (const float*)d_in[12];
    const float* Wa1 = (const float*)d_in[13]; const float* ba1 = (const float*)d_in[14];
    const float* Wa2 = (const float*)d_in[15]; const float* ba2 = (const float*)d_in[16];
    const float* Wl  = (const float*)d_in[17]; const float* bl  = (const float*)d_in[18];
    const float* Wv  = (const float*)d_in[19]; const float* bv  = (const float*)d_in[20];
    const float* Wc0 = (const float*)d_in[21]; const float* bc0 = (const float*)d_in[22];
    const float* Wc1 = (const float*)d_in[23]; const float* bc1 = (const float*)d_in[24];
    const int*   ray = (const int*)d_in[25];
    float* out = (float*)d_out;

    prep_kernel<<<dim3(1), dim3(256), 0, stream>>>(
        slots, Wb0, bb0, Wb1, bb1, Wb2, bb2,
        Wa0, ba0, Wa1, ba1, Wa2, ba2,
        Wl, bl, Wv, bv, Wc0, bc0, Wc1, bc1, (char*)d_ws);

    decoder_kernel<<<dim3(PP / 64), dim3(256), 0, stream>>>(
        coor, view, dens, shf, ray, (const char*)d_ws, out);
}